// Round 1
// baseline (19191.931 us; speedup 1.0000x reference)
//
#include <hip/hip_runtime.h>
#include <math.h>

#define T_STEPS 1024
#define B_SZ    256
#define K_DIM   128
#define IN_DIM  64
#define M_DIM   63
#define NTHREADS 512
#define VW_STRIDE 132   // padded leading dim for Vw in LDS (f32)

__launch_bounds__(NTHREADS, 2)
__global__ void lstm_fused(const float* __restrict__ x,   // [B,T,IN]
                           const float* __restrict__ Wi, const float* __restrict__ Ui,
                           const float* __restrict__ Wf, const float* __restrict__ Uf,
                           const float* __restrict__ Wg, const float* __restrict__ Ug,
                           const float* __restrict__ Wo, const float* __restrict__ Uo,
                           const float* __restrict__ Vw, const float* __restrict__ Vb,
                           float* __restrict__ out)       // [B,T,M]
{
    __shared__ __align__(16) float hbuf[K_DIM];
    __shared__ __align__(16) float xbuf[2][IN_DIM];
    __shared__ __align__(16) float zact[4 * K_DIM];
    __shared__ __align__(16) float vlds[M_DIM * VW_STRIDE];

    const int b   = blockIdx.x;
    const int tid = threadIdx.x;

    // ---- per-thread weight row: row `tid` of [Wx | Uh], Wx = concat(Wi,Wf,Wg,Wo) ----
    const int rr = tid & 127;
    const float* Wrow;
    const float* Urow;
    if (tid < 128)      { Wrow = Wi + rr * IN_DIM; Urow = Ui + rr * K_DIM; }
    else if (tid < 256) { Wrow = Wf + rr * IN_DIM; Urow = Uf + rr * K_DIM; }
    else if (tid < 384) { Wrow = Wg + rr * IN_DIM; Urow = Ug + rr * K_DIM; }
    else                { Wrow = Wo + rr * IN_DIM; Urow = Uo + rr * K_DIM; }

    float wreg[IN_DIM];
    float ureg[K_DIM];
    #pragma unroll
    for (int k = 0; k < IN_DIM / 4; ++k) {
        float4 v = ((const float4*)Wrow)[k];
        wreg[4*k+0] = v.x; wreg[4*k+1] = v.y; wreg[4*k+2] = v.z; wreg[4*k+3] = v.w;
    }
    #pragma unroll
    for (int k = 0; k < K_DIM / 4; ++k) {
        float4 v = ((const float4*)Urow)[k];
        ureg[4*k+0] = v.x; ureg[4*k+1] = v.y; ureg[4*k+2] = v.z; ureg[4*k+3] = v.w;
    }

    // ---- Vw into LDS (padded stride) ----
    for (int idx = tid; idx < M_DIM * K_DIM; idx += NTHREADS) {
        int m = idx >> 7;      // /128
        int k = idx & 127;
        vlds[m * VW_STRIDE + k] = Vw[idx];
    }

    // ---- init state, stage x_0 ----
    if (tid < K_DIM) hbuf[tid] = 0.0f;
    if (tid >= 128 && tid < 128 + IN_DIM)
        xbuf[0][tid - 128] = x[(size_t)b * T_STEPS * IN_DIM + (tid - 128)];
    float c = 0.0f;

    // y-projection role: 8 threads per output column m
    const int ym = tid >> 3;
    const int yj = tid & 7;
    float vbv = 0.0f;
    if (tid < 504 && yj == 0) vbv = Vb[ym];

    __syncthreads();

    const size_t xbase = (size_t)b * T_STEPS * IN_DIM;
    const size_t obase = (size_t)b * T_STEPS * M_DIM;

    for (int t = 0; t < T_STEPS; ++t) {
        const int cur = t & 1, nxt = cur ^ 1;

        // prefetch x_{t+1} into registers (issue early, write after mid barrier)
        float4 xpre;
        if (t + 1 < T_STEPS && tid < 16)
            xpre = ((const float4*)(x + xbase + (size_t)(t + 1) * IN_DIM))[tid];

        // ---- z[tid] = Wx[tid,:]·x_t + Uh[tid,:]·h_{t-1}  (uniform LDS broadcast reads) ----
        float z = 0.0f;
        const float4* x4 = (const float4*)xbuf[cur];
        #pragma unroll
        for (int k = 0; k < IN_DIM / 4; ++k) {
            float4 v = x4[k];
            z += wreg[4*k+0]*v.x + wreg[4*k+1]*v.y + wreg[4*k+2]*v.z + wreg[4*k+3]*v.w;
        }
        const float4* h4 = (const float4*)hbuf;
        #pragma unroll
        for (int k = 0; k < K_DIM / 4; ++k) {
            float4 v = h4[k];
            z += ureg[4*k+0]*v.x + ureg[4*k+1]*v.y + ureg[4*k+2]*v.z + ureg[4*k+3]*v.w;
        }

        // ---- deferred y_{t-1} = h_{t-1} @ Vw.T + Vb (reads hbuf before it's overwritten) ----
        if (t > 0 && tid < 504) {
            const float4* vr = (const float4*)(vlds + ym * VW_STRIDE + yj * 16);
            float p = 0.0f;
            #pragma unroll
            for (int k = 0; k < 4; ++k) {
                float4 v  = vr[k];
                float4 hh = ((const float4*)hbuf)[yj * 4 + k];
                p += v.x*hh.x + v.y*hh.y + v.z*hh.z + v.w*hh.w;
            }
            p += __shfl_xor(p, 1);
            p += __shfl_xor(p, 2);
            p += __shfl_xor(p, 4);
            if (yj == 0) out[obase + (size_t)(t - 1) * M_DIM + ym] = p + vbv;
        }

        // ---- gate activation for this thread's z ----
        float a;
        if (tid >= 256 && tid < 384) a = tanhf(z);                  // g-gate
        else                         a = 1.0f / (1.0f + __expf(-z)); // i,f,o
        zact[tid] = a;
        __syncthreads();

        // ---- state update (threads 0..127 own c[k]) ----
        if (tid < K_DIM) {
            float gi = zact[tid];
            float gf = zact[128 + tid];
            float gg = zact[256 + tid];
            float go = zact[384 + tid];
            float tc = tanhf(c);          // tanh(c_prev)
            float hn = go * tc;           // h_t = o * tanh(c_prev)   (reference quirk)
            c = gf * c + gi * gg;         // c_t = f*c_prev + i*g
            hbuf[tid] = hn;
        }
        if (t + 1 < T_STEPS && tid < 16)
            ((float4*)xbuf[nxt])[tid] = xpre;
        __syncthreads();
    }

    // ---- final y for t = T-1 ----
    if (tid < 504) {
        const float4* vr = (const float4*)(vlds + ym * VW_STRIDE + yj * 16);
        float p = 0.0f;
        #pragma unroll
        for (int k = 0; k < 4; ++k) {
            float4 v  = vr[k];
            float4 hh = ((const float4*)hbuf)[yj * 4 + k];
            p += v.x*hh.x + v.y*hh.y + v.z*hh.z + v.w*hh.w;
        }
        p += __shfl_xor(p, 1);
        p += __shfl_xor(p, 2);
        p += __shfl_xor(p, 4);
        if (yj == 0) out[obase + (size_t)(T_STEPS - 1) * M_DIM + ym] = p + vbv;
    }
}

extern "C" void kernel_launch(void* const* d_in, const int* in_sizes, int n_in,
                              void* d_out, int out_size, void* d_ws, size_t ws_size,
                              hipStream_t stream) {
    const float* x  = (const float*)d_in[0];
    const float* Wi = (const float*)d_in[1];
    const float* Ui = (const float*)d_in[2];
    const float* Wf = (const float*)d_in[3];
    const float* Uf = (const float*)d_in[4];
    const float* Wg = (const float*)d_in[5];
    const float* Ug = (const float*)d_in[6];
    const float* Wo = (const float*)d_in[7];
    const float* Uo = (const float*)d_in[8];
    const float* Vw = (const float*)d_in[9];
    const float* Vb = (const float*)d_in[10];
    float* out = (float*)d_out;

    lstm_fused<<<dim3(B_SZ), dim3(NTHREADS), 0, stream>>>(
        x, Wi, Ui, Wf, Uf, Wg, Ug, Wo, Uo, Vw, Vb, out);
}

// Round 2
// 17603.743 us; speedup vs baseline: 1.0902x; 1.0902x over previous
//
#include <hip/hip_runtime.h>
#include <math.h>

#define T_STEPS 1024
#define B_SZ    256
#define K_DIM   128
#define IN_DIM  64
#define M_DIM   63
#define NTHREADS 512
#define VW_STRIDE 132   // padded leading dim for Vw in LDS (f32)

__device__ __forceinline__ float fast_sigmoid(float z) {
    // 1/(1+e^-z); e^-z -> inf for very negative z gives rcp(inf)=0, correct.
    return __builtin_amdgcn_rcpf(1.0f + __expf(-z));
}
__device__ __forceinline__ float fast_tanh(float z) {
    z = fminf(15.0f, fmaxf(-15.0f, z));          // v_med3 clamp, avoids inf/inf
    float t = __expf(2.0f * z);
    return (t - 1.0f) * __builtin_amdgcn_rcpf(t + 1.0f);
}

__global__
__attribute__((amdgpu_flat_work_group_size(512, 512)))
__attribute__((amdgpu_waves_per_eu(2)))
void lstm_fused(const float* __restrict__ x,   // [B,T,IN]
                const float* __restrict__ Wi, const float* __restrict__ Ui,
                const float* __restrict__ Wf, const float* __restrict__ Uf,
                const float* __restrict__ Wg, const float* __restrict__ Ug,
                const float* __restrict__ Wo, const float* __restrict__ Uo,
                const float* __restrict__ Vw, const float* __restrict__ Vb,
                float* __restrict__ out)       // [B,T,M]
{
    __shared__ __align__(16) float hbuf[K_DIM];
    __shared__ __align__(16) float xbuf[2][IN_DIM];
    __shared__ __align__(16) float zact[4 * K_DIM];
    __shared__ __align__(16) float vlds[M_DIM * VW_STRIDE];

    const int b   = blockIdx.x;
    const int tid = threadIdx.x;

    // ---- per-thread weight row: row `tid` of [Wx | Uh], Wx = concat(Wi,Wf,Wg,Wo) ----
    const int rr = tid & 127;
    const float* Wrow;
    const float* Urow;
    if (tid < 128)      { Wrow = Wi + rr * IN_DIM; Urow = Ui + rr * K_DIM; }
    else if (tid < 256) { Wrow = Wf + rr * IN_DIM; Urow = Uf + rr * K_DIM; }
    else if (tid < 384) { Wrow = Wg + rr * IN_DIM; Urow = Ug + rr * K_DIM; }
    else                { Wrow = Wo + rr * IN_DIM; Urow = Uo + rr * K_DIM; }

    float4 wreg[IN_DIM / 4];   // 16 float4 = 64 VGPRs
    float4 ureg[K_DIM / 4];    // 32 float4 = 128 VGPRs
    #pragma unroll
    for (int k = 0; k < IN_DIM / 4; ++k) wreg[k] = ((const float4*)Wrow)[k];
    #pragma unroll
    for (int k = 0; k < K_DIM / 4; ++k) ureg[k] = ((const float4*)Urow)[k];

    // ---- Vw into LDS (padded stride) ----
    for (int idx = tid; idx < M_DIM * K_DIM; idx += NTHREADS) {
        int m = idx >> 7;      // /128
        int k = idx & 127;
        vlds[m * VW_STRIDE + k] = Vw[idx];
    }

    // ---- init state, stage x_0 ----
    if (tid < K_DIM) hbuf[tid] = 0.0f;
    if (tid >= 128 && tid < 128 + IN_DIM)
        xbuf[0][tid - 128] = x[(size_t)b * T_STEPS * IN_DIM + (tid - 128)];
    float c = 0.0f;

    // y-projection role: 8 threads per output column m
    const int ym = tid >> 3;
    const int yj = tid & 7;
    float vbv = 0.0f;
    if (tid < 504 && yj == 0) vbv = Vb[ym];

    __syncthreads();

    const size_t xbase = (size_t)b * T_STEPS * IN_DIM;
    const size_t obase = (size_t)b * T_STEPS * M_DIM;

    for (int t = 0; t < T_STEPS; ++t) {
        const int cur = t & 1, nxt = cur ^ 1;

        // prefetch x_{t+1} into registers (issue early, write after mid barrier)
        float4 xpre;
        if (t + 1 < T_STEPS && tid < 16)
            xpre = ((const float4*)(x + xbase + (size_t)(t + 1) * IN_DIM))[tid];

        // ---- z[tid] = Wx[tid,:]·x_t + Uh[tid,:]·h_{t-1}  (uniform LDS broadcast reads)
        // 4 independent accumulators to break the FMA dependency chain.
        float z0 = 0.f, z1 = 0.f, z2 = 0.f, z3 = 0.f;
        const float4* x4 = (const float4*)xbuf[cur];
        #pragma unroll
        for (int k = 0; k < IN_DIM / 4; k += 4) {
            float4 a0 = x4[k+0], a1 = x4[k+1], a2 = x4[k+2], a3 = x4[k+3];
            z0 += wreg[k+0].x*a0.x + wreg[k+0].y*a0.y + wreg[k+0].z*a0.z + wreg[k+0].w*a0.w;
            z1 += wreg[k+1].x*a1.x + wreg[k+1].y*a1.y + wreg[k+1].z*a1.z + wreg[k+1].w*a1.w;
            z2 += wreg[k+2].x*a2.x + wreg[k+2].y*a2.y + wreg[k+2].z*a2.z + wreg[k+2].w*a2.w;
            z3 += wreg[k+3].x*a3.x + wreg[k+3].y*a3.y + wreg[k+3].z*a3.z + wreg[k+3].w*a3.w;
        }
        const float4* h4 = (const float4*)hbuf;
        #pragma unroll
        for (int k = 0; k < K_DIM / 4; k += 4) {
            float4 a0 = h4[k+0], a1 = h4[k+1], a2 = h4[k+2], a3 = h4[k+3];
            z0 += ureg[k+0].x*a0.x + ureg[k+0].y*a0.y + ureg[k+0].z*a0.z + ureg[k+0].w*a0.w;
            z1 += ureg[k+1].x*a1.x + ureg[k+1].y*a1.y + ureg[k+1].z*a1.z + ureg[k+1].w*a1.w;
            z2 += ureg[k+2].x*a2.x + ureg[k+2].y*a2.y + ureg[k+2].z*a2.z + ureg[k+2].w*a2.w;
            z3 += ureg[k+3].x*a3.x + ureg[k+3].y*a3.y + ureg[k+3].z*a3.z + ureg[k+3].w*a3.w;
        }
        float z = (z0 + z1) + (z2 + z3);

        // ---- deferred y_{t-1} = h_{t-1} @ Vw.T + Vb (reads hbuf before overwrite) ----
        if (t > 0 && tid < 504) {
            const float4* vr = (const float4*)(vlds + ym * VW_STRIDE + yj * 16);
            float p = 0.0f;
            #pragma unroll
            for (int k = 0; k < 4; ++k) {
                float4 v  = vr[k];
                float4 hh = h4[yj * 4 + k];
                p += v.x*hh.x + v.y*hh.y + v.z*hh.z + v.w*hh.w;
            }
            p += __shfl_xor(p, 1);
            p += __shfl_xor(p, 2);
            p += __shfl_xor(p, 4);
            if (yj == 0) out[obase + (size_t)(t - 1) * M_DIM + ym] = p + vbv;
        }

        // ---- gate activation for this thread's z (wave-uniform branch) ----
        float a;
        if (tid >= 256 && tid < 384) a = fast_tanh(z);     // g-gate
        else                         a = fast_sigmoid(z);  // i,f,o
        zact[tid] = a;
        __syncthreads();

        // ---- state update (threads 0..127 own c[k]) ----
        if (tid < K_DIM) {
            float gi = zact[tid];
            float gf = zact[128 + tid];
            float gg = zact[256 + tid];
            float go = zact[384 + tid];
            float tc = fast_tanh(c);      // tanh(c_prev)
            float hn = go * tc;           // h_t = o * tanh(c_prev)   (reference quirk)
            c = gf * c + gi * gg;         // c_t = f*c_prev + i*g
            hbuf[tid] = hn;
        }
        if (t + 1 < T_STEPS && tid < 16)
            ((float4*)xbuf[nxt])[tid] = xpre;
        __syncthreads();
    }

    // ---- final y for t = T-1 ----
    if (tid < 504) {
        const float4* vr = (const float4*)(vlds + ym * VW_STRIDE + yj * 16);
        float p = 0.0f;
        #pragma unroll
        for (int k = 0; k < 4; ++k) {
            float4 v  = vr[k];
            float4 hh = ((const float4*)hbuf)[yj * 4 + k];
            p += v.x*hh.x + v.y*hh.y + v.z*hh.z + v.w*hh.w;
        }
        p += __shfl_xor(p, 1);
        p += __shfl_xor(p, 2);
        p += __shfl_xor(p, 4);
        if (yj == 0) out[obase + (size_t)(T_STEPS - 1) * M_DIM + ym] = p + vbv;
    }
}

extern "C" void kernel_launch(void* const* d_in, const int* in_sizes, int n_in,
                              void* d_out, int out_size, void* d_ws, size_t ws_size,
                              hipStream_t stream) {
    const float* x  = (const float*)d_in[0];
    const float* Wi = (const float*)d_in[1];
    const float* Ui = (const float*)d_in[2];
    const float* Wf = (const float*)d_in[3];
    const float* Uf = (const float*)d_in[4];
    const float* Wg = (const float*)d_in[5];
    const float* Ug = (const float*)d_in[6];
    const float* Wo = (const float*)d_in[7];
    const float* Uo = (const float*)d_in[8];
    const float* Vw = (const float*)d_in[9];
    const float* Vb = (const float*)d_in[10];
    float* out = (float*)d_out;

    lstm_fused<<<dim3(B_SZ), dim3(NTHREADS), 0, stream>>>(
        x, Wi, Ui, Wf, Uf, Wg, Ug, Wo, Uo, Vw, Vb, out);
}